// Round 13
// baseline (23.471 us; speedup 1.0000x reference)
//
#include <hip/hip_runtime.h>

#define N 512
#define SLICE (512 * 512)
#define KAPPA2 0.1089f   // 0.33^2
#define GAMMA  1.0f
#define BETA   25.0f

// Wave = full row: lane L owns px [8L, 8L+8). Span s[0..9] covers [8L-1, 8L+8].
// Edges via shuffle; lane 0 / 63 get the Dirichlet zero boundary.
__device__ __forceinline__ void loadspan10(const float* __restrict__ p, int lane,
                                           float s[10]) {
    const float4 A = *reinterpret_cast<const float4*>(p);
    const float4 B = *reinterpret_cast<const float4*>(p + 4);
    s[1] = A.x; s[2] = A.y; s[3] = A.z; s[4] = A.w;
    s[5] = B.x; s[6] = B.y; s[7] = B.z; s[8] = B.w;
    const float lw = __shfl_up(B.w, 1, 64);
    const float rx = __shfl_down(A.x, 1, 64);
    s[0] = (lane == 0)  ? 0.0f : lw;
    s[9] = (lane == 63) ? 0.0f : rx;
}

__device__ __forceinline__ void zero10(float s[10]) {
    #pragma unroll
    for (int j = 0; j < 10; ++j) s[j] = 0.0f;
}

// state: [B=8, 9, 512, 512] f32. slices 0..6 = x_t, 7 = vx, 8 = vy.
// q decomposition (per slice t, summed over pixels):
//   t=0: |Ax0|^2 + 1.05|x0|^2;  t=1..5: |Mx_t|^2 - 2 x_{t-1}.Mx_t + |x_t|^2;
//   t=6: |Mx_6|^2 - 2 x_5.Mx_6.
// Branch-free per-pixel: val = m*c + Ax (m=0 -> Ax at t=0, else Mx);
//   q += val^2 - 2*xp*val + ccoef*c^2;  xp = x_{t-1} = previous t's center
//   span (registers). H computed once per wave, reused across its t-range.
// Stage 1: one wave per (b, y, g); g=0 -> t=0..3, g=1 -> t=4..6 (loads x_3
// once for its first cross term). bid = (y*2+g)*8 + b: %8 round-robin pins
// batch->XCD; the two t-halves of a row are adjacent (vx/vy rows L2-hot).
// 8192 one-wave blocks = 8 waves/SIMD: latency-hiding budget ~2800 cyc.
__global__ __launch_bounds__(64) void phi_q_stage1(const float* __restrict__ state,
                                                   float* __restrict__ ws) {
    const int bid  = blockIdx.x;       // 8192 = 512 * 2 * 8
    const int b    = bid & 7;
    const int yg   = bid >> 3;         // y*2 + g
    const int y    = yg >> 1;
    const int g    = yg & 1;
    const int lane = threadIdx.x;
    const int xo   = lane * 8;

    const float* base = state + (size_t)b * 9 * SLICE;
    const size_t ro   = (size_t)y * N + xo;

    const bool ym = (y > 0), yp = (y < N - 1);   // wave-uniform

    // Diffusion tensor for this row's 8 px: computed once, reused for 3-4 t.
    float H11[8], H12[8], H22[8];
    {
        const float4 vxA = *reinterpret_cast<const float4*>(base + 7 * SLICE + ro);
        const float4 vxB = *reinterpret_cast<const float4*>(base + 7 * SLICE + ro + 4);
        const float4 vyA = *reinterpret_cast<const float4*>(base + 8 * SLICE + ro);
        const float4 vyB = *reinterpret_cast<const float4*>(base + 8 * SLICE + ro + 4);
        const float vxs[8] = {vxA.x, vxA.y, vxA.z, vxA.w, vxB.x, vxB.y, vxB.z, vxB.w};
        const float vys[8] = {vyA.x, vyA.y, vyA.z, vyA.w, vyB.x, vyB.y, vyB.z, vyB.w};
        #pragma unroll
        for (int j = 0; j < 8; ++j) {
            H11[j] = GAMMA + BETA * vxs[j] * vxs[j];
            H12[j] = 2.0f * BETA * vxs[j] * vys[j];
            H22[j] = GAMMA + BETA * vys[j] * vys[j];
        }
    }

    const int tbeg = g ? 4 : 0;
    const int tend = g ? 7 : 4;

    // Cross-term seed: g=0 -> zeros (t=0 has no cross term); g=1 -> x_3 row.
    float xprev[8];
    if (g) {
        const float* x3 = base + 3 * SLICE + ro;
        const float4 XA = *reinterpret_cast<const float4*>(x3);
        const float4 XB = *reinterpret_cast<const float4*>(x3 + 4);
        xprev[0] = XA.x; xprev[1] = XA.y; xprev[2] = XA.z; xprev[3] = XA.w;
        xprev[4] = XB.x; xprev[5] = XB.y; xprev[6] = XB.z; xprev[7] = XB.w;
    } else {
        #pragma unroll
        for (int j = 0; j < 8; ++j) xprev[j] = 0.0f;
    }

    float q = 0.0f;
    float m = g ? 1.0f : 0.0f;     // 0 only at t=0 (val=Ax), 1 after (val=Mx)

    #pragma unroll 1               // keep rolled: avoid load hoisting / VGPR blowup
    for (int t = tbeg; t < tend; ++t) {
        const float* u = base + (size_t)t * SLICE;
        float sm[10], sc[10], su[10];
        loadspan10(u + ro, lane, sc);
        if (ym) loadspan10(u + ro - N, lane, sm);
        else    zero10(sm);
        if (yp) loadspan10(u + ro + N, lane, su);
        else    zero10(su);

        const float ccoef = (t == 0) ? 1.05f : ((t < 6) ? 1.0f : 0.0f);

        #pragma unroll
        for (int j = 0; j < 8; ++j) {
            const float c   = sc[j + 1];
            const float uxx = sc[j] + sc[j + 2] - 2.0f * c;
            const float uyy = sm[j + 1] + su[j + 1] - 2.0f * c;
            const float uxy = 0.25f * (su[j + 2] - su[j] - sm[j + 2] + sm[j]);
            const float div = H11[j] * uxx + H12[j] * uxy + H22[j] * uyy;
            const float Ax  = KAPPA2 * c - div;
            const float val = m * c + Ax;            // Ax at t=0, Mx else
            q += val * val - 2.0f * xprev[j] * val + ccoef * c * c;
            xprev[j] = c;                            // x_t for next iteration
        }
        m = 1.0f;
    }

    // wave reduce -> one partial per wave; ws[b*1024 + yg] contiguous per batch.
    #pragma unroll
    for (int off = 32; off > 0; off >>= 1)
        q += __shfl_down(q, off, 64);

    if (lane == 0) ws[b * 1024 + yg] = q;
}

// Stage 2: 8 blocks; block b sums its contiguous 1024 partials.
__global__ __launch_bounds__(256) void phi_q_stage2(const float* __restrict__ ws,
                                                    float* __restrict__ out) {
    const int b = blockIdx.x;
    const float* p = ws + b * 1024;
    float v = p[threadIdx.x] + p[threadIdx.x + 256]
            + p[threadIdx.x + 512] + p[threadIdx.x + 768];

    #pragma unroll
    for (int off = 32; off > 0; off >>= 1)
        v += __shfl_down(v, off, 64);

    __shared__ float sred[4];
    const int lane = threadIdx.x & 63;
    const int wid  = threadIdx.x >> 6;
    if (lane == 0) sred[wid] = v;
    __syncthreads();
    if (threadIdx.x == 0) out[b] = sred[0] + sred[1] + sred[2] + sred[3];
}

extern "C" void kernel_launch(void* const* d_in, const int* in_sizes, int n_in,
                              void* d_out, int out_size, void* d_ws, size_t ws_size,
                              hipStream_t stream) {
    const float* state = (const float*)d_in[0];
    float* out = (float*)d_out;
    float* ws  = (float*)d_ws;

    phi_q_stage1<<<8192, 64, 0, stream>>>(state, ws);
    phi_q_stage2<<<8, 256, 0, stream>>>(ws, out);
}

// Round 14
// 20.966 us; speedup vs baseline: 1.1195x; 1.1195x over previous
//
#include <hip/hip_runtime.h>

#define N 512
#define SLICE (512 * 512)
#define KAPPA2 0.1089f   // 0.33^2
#define GAMMA  1.0f
#define BETA   25.0f

// Raw 3-row tile of one slice at one row: center/minus/plus rows, 8 px each.
struct Tile { float4 cA, cB, mA, mB, uA, uB; };

__device__ __forceinline__ void loadtile(const float* __restrict__ u, size_t ro,
                                         bool ym, bool yp, Tile& T) {
    T.cA = *reinterpret_cast<const float4*>(u + ro);
    T.cB = *reinterpret_cast<const float4*>(u + ro + 4);
    if (ym) {
        T.mA = *reinterpret_cast<const float4*>(u + ro - N);
        T.mB = *reinterpret_cast<const float4*>(u + ro - N + 4);
    } else {
        T.mA = float4{0.f, 0.f, 0.f, 0.f}; T.mB = float4{0.f, 0.f, 0.f, 0.f};
    }
    if (yp) {
        T.uA = *reinterpret_cast<const float4*>(u + ro + N);
        T.uB = *reinterpret_cast<const float4*>(u + ro + N + 4);
    } else {
        T.uA = float4{0.f, 0.f, 0.f, 0.f}; T.uB = float4{0.f, 0.f, 0.f, 0.f};
    }
}

// Wave = full row: lane L owns px [8L, 8L+8). Span s[0..9] covers [8L-1, 8L+8].
__device__ __forceinline__ void span_from(const float4& A, const float4& B, int lane,
                                          float s[10]) {
    s[1] = A.x; s[2] = A.y; s[3] = A.z; s[4] = A.w;
    s[5] = B.x; s[6] = B.y; s[7] = B.z; s[8] = B.w;
    const float lw = __shfl_up(B.w, 1, 64);
    const float rx = __shfl_down(A.x, 1, 64);
    s[0] = (lane == 0)  ? 0.0f : lw;
    s[9] = (lane == 63) ? 0.0f : rx;
}

// One slice's contribution at this row. val = m*c + Ax (m=0 at t=0 -> Ax, else Mx);
// q += val^2 - 2*xprev*val + ccoef*c^2; xprev <- c (x_t for the next t).
__device__ __forceinline__ void compute_tile(const Tile& T, int lane,
                                             const float* H11, const float* H12,
                                             const float* H22, float* xprev,
                                             float m, float ccoef, float& q) {
    float sm[10], sc[10], su[10];
    span_from(T.cA, T.cB, lane, sc);
    span_from(T.mA, T.mB, lane, sm);
    span_from(T.uA, T.uB, lane, su);

    #pragma unroll
    for (int j = 0; j < 8; ++j) {
        const float c   = sc[j + 1];
        const float uxx = sc[j] + sc[j + 2] - 2.0f * c;
        const float uyy = sm[j + 1] + su[j + 1] - 2.0f * c;
        const float uxy = 0.25f * (su[j + 2] - su[j] - sm[j + 2] + sm[j]);
        const float div = H11[j] * uxx + H12[j] * uxy + H22[j] * uyy;
        const float Ax  = KAPPA2 * c - div;
        const float val = m * c + Ax;
        q += val * val - 2.0f * xprev[j] * val + ccoef * c * c;
        xprev[j] = c;
    }
}

// state: [B=8, 9, 512, 512] f32. slices 0..6 = x_t, 7 = vx, 8 = vy.
// q per slice t: t=0: |Ax0|^2+1.05|x0|^2; t=1..5: |Mx|^2-2x_{t-1}.Mx+|x|^2;
// t=6: |Mx|^2-2x_5.Mx. Cross term from registers; H loaded once per row.
// Stage 1: one wave per (b, y); software-pipelined t-loop (ping-pong tiles):
// issue slice t+1's loads before computing slice t -> waits overlap compute.
__global__ __launch_bounds__(64, 4) void phi_q_stage1(const float* __restrict__ state,
                                                      float* __restrict__ ws) {
    const int bid  = blockIdx.x;       // 4096 = 512 * 8
    const int b    = bid & 7;          // batch == XCD (round-robin dispatch)
    const int y    = bid >> 3;
    const int lane = threadIdx.x;
    const int xo   = lane * 8;

    const float* base = state + (size_t)b * 9 * SLICE;
    const size_t ro   = (size_t)y * N + xo;

    const bool ym = (y > 0), yp = (y < N - 1);   // wave-uniform

    // Diffusion tensor for this row's 8 px: computed once, reused for all 7 t.
    float H11[8], H12[8], H22[8];
    {
        const float4 vxA = *reinterpret_cast<const float4*>(base + 7 * SLICE + ro);
        const float4 vxB = *reinterpret_cast<const float4*>(base + 7 * SLICE + ro + 4);
        const float4 vyA = *reinterpret_cast<const float4*>(base + 8 * SLICE + ro);
        const float4 vyB = *reinterpret_cast<const float4*>(base + 8 * SLICE + ro + 4);
        const float vxs[8] = {vxA.x, vxA.y, vxA.z, vxA.w, vxB.x, vxB.y, vxB.z, vxB.w};
        const float vys[8] = {vyA.x, vyA.y, vyA.z, vyA.w, vyB.x, vyB.y, vyB.z, vyB.w};
        #pragma unroll
        for (int j = 0; j < 8; ++j) {
            H11[j] = GAMMA + BETA * vxs[j] * vxs[j];
            H12[j] = 2.0f * BETA * vxs[j] * vys[j];
            H22[j] = GAMMA + BETA * vys[j] * vys[j];
        }
    }

    float xprev[8];
    #pragma unroll
    for (int j = 0; j < 8; ++j) xprev[j] = 0.0f;

    float q = 0.0f;

    // Ping-pong pipeline over t = 0..6 (named buffers; no dynamic indexing).
    Tile Ta, Tb;
    loadtile(base, ro, ym, yp, Ta);                            // t = 0

    #pragma unroll 1
    for (int t = 0; t < 6; t += 2) {
        loadtile(base + (size_t)(t + 1) * SLICE, ro, ym, yp, Tb);
        {   // compute slice t on Ta
            const float m     = (t == 0) ? 0.0f : 1.0f;
            const float ccoef = (t == 0) ? 1.05f : 1.0f;      // t in {0,2,4}
            compute_tile(Ta, lane, H11, H12, H22, xprev, m, ccoef, q);
        }
        loadtile(base + (size_t)(t + 2) * SLICE, ro, ym, yp, Ta);
        {   // compute slice t+1 on Tb  (t+1 in {1,3,5} -> m=1, ccoef=1)
            compute_tile(Tb, lane, H11, H12, H22, xprev, 1.0f, 1.0f, q);
        }
    }
    // epilogue: slice 6 (loaded into Ta at t=4 iteration), no |x|^2 term.
    compute_tile(Ta, lane, H11, H12, H22, xprev, 1.0f, 0.0f, q);

    // wave reduce -> one partial per wave; ws[b*512 + y] contiguous per batch.
    #pragma unroll
    for (int off = 32; off > 0; off >>= 1)
        q += __shfl_down(q, off, 64);

    if (lane == 0) ws[b * 512 + y] = q;
}

// Stage 2: 8 blocks; block b sums its contiguous 512 partials.
__global__ __launch_bounds__(256) void phi_q_stage2(const float* __restrict__ ws,
                                                    float* __restrict__ out) {
    const int b = blockIdx.x;
    const float* p = ws + b * 512;
    float v = p[threadIdx.x] + p[threadIdx.x + 256];

    #pragma unroll
    for (int off = 32; off > 0; off >>= 1)
        v += __shfl_down(v, off, 64);

    __shared__ float sred[4];
    const int lane = threadIdx.x & 63;
    const int wid  = threadIdx.x >> 6;
    if (lane == 0) sred[wid] = v;
    __syncthreads();
    if (threadIdx.x == 0) out[b] = sred[0] + sred[1] + sred[2] + sred[3];
}

extern "C" void kernel_launch(void* const* d_in, const int* in_sizes, int n_in,
                              void* d_out, int out_size, void* d_ws, size_t ws_size,
                              hipStream_t stream) {
    const float* state = (const float*)d_in[0];
    float* out = (float*)d_out;
    float* ws  = (float*)d_ws;

    phi_q_stage1<<<4096, 64, 0, stream>>>(state, ws);
    phi_q_stage2<<<8, 256, 0, stream>>>(ws, out);
}